// Round 9
// baseline (74.315 us; speedup 1.0000x reference)
//
#include <hip/hip_runtime.h>
#include <hip/hip_bf16.h>
#include <cstdint>

// PiNet: B=8192, I=12, O=512, DEG=4.
// Symmetry-folded to T = 1820 monomials (padded to 1856 = 29*64).
// R8: (a) gen fast path -- consecutive rank2(c,d) within an (a,b) block lets a
// 4-monomial quad use 1 b32 + 1 b64 LDS read (4-shift fp16 msm copies);
// (b) 32b x 64o waves halve A-frag duplication; (c) fold stages fp16 (2 blk/CU).

#define NB 8192
#define NI 12
#define NO 512
#define T_TOTAL 1820
#define TPAD 1856          // 29 * 64
#define NKT 29
#define B2 13
#define B3 91
#define B4 455
#define NQUAD (TPAD / 4)   // 464

typedef __attribute__((ext_vector_type(8))) _Float16 f16x8;
typedef __attribute__((ext_vector_type(4))) float f32x4;

#define MFMA16(a, b, c) __builtin_amdgcn_mfma_f32_16x16x32_f16(a, b, c, 0, 0, 0)

__device__ __forceinline__ int H2f(int n) { return n * (n + 1) / 2; }
__device__ __forceinline__ int H3f(int n) { return n * (n + 1) * (n + 2) / 6; }
__device__ __forceinline__ int rank2(int a, int b) {
    int r = 0;
    for (int j = 0; j < a; ++j) r += NI - j;
    return r + (b - a);
}
__device__ __forceinline__ unsigned short f2h(float f) {
    _Float16 h = (_Float16)f;
    return __builtin_bit_cast(unsigned short, h);
}
__device__ __forceinline__ float h2f(unsigned short u) {
    return (float)__builtin_bit_cast(_Float16, u);
}

// ---------- maps: mp (pair table), mp2 (quad fast-path), tup/rk (fold orbits) --
__global__ __launch_bounds__(256) void pinet_maps(
    uint32_t* __restrict__ mp, uint32_t* __restrict__ mp2,
    ushort* __restrict__ tup2, float* __restrict__ rk2,
    ushort* __restrict__ tup3, float* __restrict__ rk3,
    ushort* __restrict__ tup4, float* __restrict__ rk4) {
    int id = blockIdx.x * 256 + threadIdx.x;
    if (id < TPAD) {
        int t = id;
        uint32_t v = 0;
        if (t == 0) {
            v = 0;
        } else if (t < B2) {
            v = (uint32_t)t;
        } else if (t < B3) {
            int r = t - B2;
            int a = 0; while (r >= (NI - a)) { r -= (NI - a); ++a; }
            int b = a + r;
            v = (uint32_t)(1 + a) | ((uint32_t)(1 + b) << 16);
        } else if (t < B4) {
            int r = t - B3;
            int a = 0; while (r >= H2f(NI - a)) { r -= H2f(NI - a); ++a; }
            int b = a; while (r >= (NI - b)) { r -= (NI - b); ++b; }
            int c = b + r;
            v = (uint32_t)(13 + rank2(a, b)) | ((uint32_t)(1 + c) << 16);
        } else if (t < T_TOTAL) {
            int r = t - B4;
            int a = 0; while (r >= H3f(NI - a)) { r -= H3f(NI - a); ++a; }
            int b = a; while (r >= H2f(NI - b)) { r -= H2f(NI - b); ++b; }
            int c = b; while (r >= (NI - c)) { r -= (NI - c); ++c; }
            int d = c + r;
            v = (uint32_t)(13 + rank2(a, b)) | ((uint32_t)(13 + rank2(c, d)) << 16);
        }
        mp[t] = v;     // t in [1820,1856): monomial = 1, weight 0
        return;
    }
    id -= TPAD;
    if (id < NQUAD) {                     // quad fast-path descriptors
        int t0 = id * 4;
        uint32_t e = 0;
        if (t0 >= B4 && t0 + 3 < T_TOTAL) {
            int r = t0 - B4;
            int a0 = 0; while (r >= H3f(NI - a0)) { r -= H3f(NI - a0); ++a0; }
            int b0 = a0; while (r >= H2f(NI - b0)) { r -= H2f(NI - b0); ++b0; }
            int c0 = b0; while (r >= (NI - c0)) { r -= (NI - c0); ++c0; }
            int d0 = c0 + r;
            int r3 = t0 + 3 - B4;
            int a3 = 0; while (r3 >= H3f(NI - a3)) { r3 -= H3f(NI - a3); ++a3; }
            int b3 = a3; while (r3 >= H2f(NI - b3)) { r3 -= H2f(NI - b3); ++b3; }
            if (a0 == a3 && b0 == b3) {
                uint32_t off1 = 13 + rank2(a0, b0);
                uint32_t off2 = 13 + rank2(c0, d0);
                e = 0x80000000u | (off1 << 8) | off2;
            }
        }
        mp2[id] = e;
        return;
    }
    id -= NQUAD;
    if (id < 1365) {                      // degree 4 orbit descriptor
        int r = id;
        int a = 0; while (r >= H3f(NI - a)) { r -= H3f(NI - a); ++a; }
        int b = a; while (r >= H2f(NI - b)) { r -= H2f(NI - b); ++b; }
        int c = b; while (r >= (NI - c)) { r -= (NI - c); ++c; }
        int d = c + r;
        tup4[id] = (ushort)(a | (b << 4) | (c << 8) | (d << 12));
        int k = 1, run = 1;
        if (b == a) { ++run; k *= run; } else run = 1;
        if (c == b) { ++run; k *= run; } else run = 1;
        if (d == c) { ++run; k *= run; } else run = 1;
        rk4[id] = 1.0f / (float)k;
        return;
    }
    id -= 1365;
    if (id < 364) {                       // degree 3
        int r = id;
        int a = 0; while (r >= H2f(NI - a)) { r -= H2f(NI - a); ++a; }
        int b = a; while (r >= (NI - b)) { r -= (NI - b); ++b; }
        int c = b + r;
        tup3[id] = (ushort)(a | (b << 4) | (c << 8));
        int k = 1, run = 1;
        if (b == a) { ++run; k *= run; } else run = 1;
        if (c == b) { ++run; k *= run; } else run = 1;
        rk3[id] = 1.0f / (float)k;
        return;
    }
    id -= 364;
    if (id < 78) {                        // degree 2
        int r = id;
        int a = 0; while (r >= (NI - a)) { r -= (NI - a); ++a; }
        int b = a + r;
        tup2[id] = (ushort)(a | (b << 4));
        rk2[id] = (a == b) ? 0.5f : 1.0f;
    }
}

// ---------- fold: fp16 LDS staging + per-t orbit gather, plain stores ----------
// One block (1024 threads) per o; 45 KB LDS -> 2 blocks/CU.
__global__ __launch_bounds__(1024, 8) void pinet_fold(
    const float* __restrict__ w0, const float* __restrict__ w1,
    const float* __restrict__ w2, const float* __restrict__ w3,
    const float* __restrict__ w4,
    const ushort* __restrict__ tup2, const float* __restrict__ rk2,
    const ushort* __restrict__ tup3, const float* __restrict__ rk3,
    const ushort* __restrict__ tup4, const float* __restrict__ rk4,
    ushort* __restrict__ Wh) {
    __shared__ ushort sw4h[20736];
    __shared__ ushort sw3h[1728];
    __shared__ ushort sw2h[144];
    const int tid = threadIdx.x;
    const int o = blockIdx.x;

    {   // coalesced staging, f32 -> fp16
        const float4* g4 = (const float4*)(w4 + o * 20736);
        for (int i = tid; i < 5184; i += 1024) {
            float4 v = g4[i];
            ushort4 h = {f2h(v.x), f2h(v.y), f2h(v.z), f2h(v.w)};
            *(ushort4*)&sw4h[i * 4] = h;
        }
        if (tid < 432) {
            float4 v = ((const float4*)(w3 + o * 1728))[tid];
            ushort4 h = {f2h(v.x), f2h(v.y), f2h(v.z), f2h(v.w)};
            *(ushort4*)&sw3h[tid * 4] = h;
        }
        if (tid < 36) {
            float4 v = ((const float4*)(w2 + o * 144))[tid];
            ushort4 h = {f2h(v.x), f2h(v.y), f2h(v.z), f2h(v.w)};
            *(ushort4*)&sw2h[tid * 4] = h;
        }
    }
    __syncthreads();

#define W4P(p, q, r, s_) h2f(sw4h[(p) * 1728 + (q) * 144 + (r) * 12 + (s_)])
#define W3P(p, q, r)     h2f(sw3h[(p) * 144 + (q) * 12 + (r)])
    for (int t = tid; t < TPAD; t += 1024) {
        float s = 0.0f;
        if (t == 0) {
            s = w0[o];
        } else if (t < B2) {
            s = w1[o * 12 + (t - 1)];
        } else if (t < B3) {
            int q = t - B2; int tp = tup2[q];
            int a = tp & 15, b = (tp >> 4) & 15;
            s = (h2f(sw2h[a * 12 + b]) + h2f(sw2h[b * 12 + a])) * rk2[q];
        } else if (t < B4) {
            int q = t - B3; int tp = tup3[q];
            int a = tp & 15, b = (tp >> 4) & 15, c = (tp >> 8) & 15;
            s = (W3P(a, b, c) + W3P(a, c, b) + W3P(b, a, c) +
                 W3P(b, c, a) + W3P(c, a, b) + W3P(c, b, a)) * rk3[q];
        } else if (t < T_TOTAL) {
            int q = t - B4; int tp = tup4[q];
            int a = tp & 15, b = (tp >> 4) & 15, c = (tp >> 8) & 15, d = (tp >> 12) & 15;
            float s4v =
                W4P(a,b,c,d) + W4P(a,b,d,c) + W4P(a,c,b,d) + W4P(a,c,d,b) +
                W4P(a,d,b,c) + W4P(a,d,c,b) + W4P(b,a,c,d) + W4P(b,a,d,c) +
                W4P(b,c,a,d) + W4P(b,c,d,a) + W4P(b,d,a,c) + W4P(b,d,c,a) +
                W4P(c,a,b,d) + W4P(c,a,d,b) + W4P(c,b,a,d) + W4P(c,b,d,a) +
                W4P(c,d,a,b) + W4P(c,d,b,a) + W4P(d,a,b,c) + W4P(d,a,c,b) +
                W4P(d,b,a,c) + W4P(d,b,c,a) + W4P(d,c,a,b) + W4P(d,c,b,a);
            s = s4v * rk4[q];
        }
        Wh[((t >> 3) * NO + o) * 8 + (t & 7)] = f2h(s);
    }
#undef W4P
#undef W3P
}

// ---------- MFMA GEMM: out[b,o] = sum_t M[t][b] * Wt[t][o], fp16 ----------
// Block: 64 b x 256 o, 512 threads (8 waves = 2wB x 4wO), wave 32b x 64o, KT=64.
// A generated on the fly (quad fast path) into double-buffered swizzled LDS.
__global__ __launch_bounds__(512, 2) void pinet_gemm(
    const float* __restrict__ x, const ushort* __restrict__ Wh,
    const uint32_t* __restrict__ mp, const uint32_t* __restrict__ mp2,
    float* __restrict__ out) {
    __shared__ float msm[64][93];         // per-b: {1, x0..x11, 78 deg2} fp32
    __shared__ ushort row4[64][388];      // 4-shift fp16 copies of msm[0..92]
    __shared__ ushort Ash[2][64][8][8];   // [buf][b][t-octet slot (swizzled)][8]

    const int tid = threadIdx.x;
    const int blkB = blockIdx.x >> 1;
    const int blkO = blockIdx.x & 1;
    const int b0 = blkB * 64;

    for (int idx = tid; idx < 64 * 13; idx += 512) {
        int b = idx / 13, j = idx % 13;
        msm[b][j] = (j == 0) ? 1.0f : x[(b0 + b) * 12 + (j - 1)];
    }
    __syncthreads();
    for (int idx = tid; idx < 64 * 78; idx += 512) {
        int b = idx / 78, q = idx % 78;
        uint32_t m2 = mp[B2 + q];
        msm[b][13 + q] = msm[b][m2 & 0xFFFFu] * msm[b][m2 >> 16];
    }
    __syncthreads();
    // build shifted fp16 copies: row4[b][s*96 + k*4 + j] = fp16(msm[b][4k+s+j])
    for (int idx = tid; idx < 64 * 96; idx += 512) {
        int b = idx / 96, slot = idx % 96, s = slot / 24, k = slot % 24;
        int base = 4 * k + s;
        ushort4 h;
        h.x = (base + 0 <= 92) ? f2h(msm[b][base + 0]) : (ushort)0;
        h.y = (base + 1 <= 92) ? f2h(msm[b][base + 1]) : (ushort)0;
        h.z = (base + 2 <= 92) ? f2h(msm[b][base + 2]) : (ushort)0;
        h.w = (base + 3 <= 92) ? f2h(msm[b][base + 3]) : (ushort)0;
        *(ushort4*)&row4[b][s * 96 + k * 4] = h;
    }

    const int l = tid & 63, wv = tid >> 6;
    const int lm = l & 15, lg = l >> 4;
    const int wB = wv >> 2, wO = wv & 3;
    const int o_w = blkO * 256 + wO * 64;
    const int bgen = tid & 63;

    f32x4 acc[2][4] = {};                 // [bs][os]
    f16x8 B0[4][2], B1[4][2];             // [os][c]

    auto gen = [&](int kt, int buf) {
#pragma unroll
        for (int jj = 0; jj < 2; ++jj) {
            const int task = wv + jj * 8;          // wave-uniform
            const uint32_t e = mp2[kt * 16 + task];
            float p0, p1, p2, p3;
            if ((int)e < 0) {                      // fast: shared * consecutive
                const float m1 = msm[bgen][(e >> 8) & 0x7Fu];
                const int off2 = e & 0x7Fu;
                ushort4 qv = *(const ushort4*)
                    &row4[bgen][(off2 & 3) * 96 + (off2 >> 2) * 4];
                p0 = m1 * h2f(qv.x); p1 = m1 * h2f(qv.y);
                p2 = m1 * h2f(qv.z); p3 = m1 * h2f(qv.w);
            } else {                               // slow: generic pair table
                const int t0 = kt * 64 + task * 4;
                uint4 mq = *(const uint4*)&mp[t0];
                p0 = msm[bgen][mq.x & 0xFFFFu] * msm[bgen][mq.x >> 16];
                p1 = msm[bgen][mq.y & 0xFFFFu] * msm[bgen][mq.y >> 16];
                p2 = msm[bgen][mq.z & 0xFFFFu] * msm[bgen][mq.z >> 16];
                p3 = msm[bgen][mq.w & 0xFFFFu] * msm[bgen][mq.w >> 16];
            }
            ushort4 v = {f2h(p0), f2h(p1), f2h(p2), f2h(p3)};
            *(ushort4*)&Ash[buf][bgen][(task >> 1) ^ (bgen & 7)][(task & 1) * 4] = v;
        }
    };
    auto loadB = [&](int kt, f16x8 (&B)[4][2]) {
#pragma unroll
        for (int os = 0; os < 4; ++os)
#pragma unroll
            for (int c = 0; c < 2; ++c) {
                int pk = kt * 8 + c * 4 + lg;
                B[os][c] = *(const f16x8*)
                    (Wh + ((size_t)pk * NO + o_w + os * 16 + lm) * 8);
            }
    };
    auto mfmaR = [&](int cur, f16x8 (&B)[4][2]) {
#pragma unroll
        for (int c = 0; c < 2; ++c) {
            f16x8 a0 = *(const f16x8*)
                &Ash[cur][wB * 32 + lm][(c * 4 + lg) ^ (lm & 7)][0];
            f16x8 a1 = *(const f16x8*)
                &Ash[cur][wB * 32 + 16 + lm][(c * 4 + lg) ^ (lm & 7)][0];
#pragma unroll
            for (int os = 0; os < 4; ++os) {
                acc[0][os] = MFMA16(a0, B[os][c], acc[0][os]);
                acc[1][os] = MFMA16(a1, B[os][c], acc[1][os]);
            }
        }
    };

    __syncthreads();          // msm + row4 ready
    gen(0, 0);
    loadB(0, B0);
    __syncthreads();          // Ash[0] ready

    for (int kt2 = 0; kt2 < 28; kt2 += 2) {
        loadB(kt2 + 1, B1);
        gen(kt2 + 1, 1);
        mfmaR(0, B0);
        __syncthreads();
        loadB(kt2 + 2, B0);   // kt2+2 <= 28 = NKT-1 always valid
        gen(kt2 + 2, 0);
        mfmaR(1, B1);
        __syncthreads();
    }
    mfmaR(0, B0);             // kt = 28

#pragma unroll
    for (int bs = 0; bs < 2; ++bs)
#pragma unroll
        for (int os = 0; os < 4; ++os) {
            int ob = o_w + os * 16 + lm;
#pragma unroll
            for (int r = 0; r < 4; ++r) {
                int bb = b0 + wB * 32 + bs * 16 + lg * 4 + r;
                out[bb * NO + ob] = acc[bs][os][r];
            }
        }
}

extern "C" void kernel_launch(void* const* d_in, const int* in_sizes, int n_in,
                              void* d_out, int out_size, void* d_ws, size_t ws_size,
                              hipStream_t stream) {
    const float* x  = (const float*)d_in[0];
    const float* w0 = (const float*)d_in[1];
    const float* w1 = (const float*)d_in[2];
    const float* w2 = (const float*)d_in[3];
    const float* w3 = (const float*)d_in[4];
    const float* w4 = (const float*)d_in[5];
    float* out = (float*)d_out;

    uint8_t* ws = (uint8_t*)d_ws;
    uint32_t* mp  = (uint32_t*)ws;                 // 7424 B (pad 8192)
    uint32_t* mp2 = (uint32_t*)(ws + 8192);        // 1856 B (pad 2048)
    ushort* tup4  = (ushort*)(ws + 10240);         // 2730 B (pad 3072)
    float*  rk4   = (float*)(ws + 13312);          // 5460 B (pad 5632)
    ushort* tup3  = (ushort*)(ws + 18944);         // 728 B  (pad 1024)
    float*  rk3   = (float*)(ws + 19968);          // 1456 B (pad 1536)
    ushort* tup2  = (ushort*)(ws + 21504);         // 156 B  (pad 512)
    float*  rk2   = (float*)(ws + 22016);          // 312 B  (pad 512)
    ushort* Wh    = (ushort*)(ws + 22528);         // 232*512*8*2 = 1,900,544 B

    pinet_maps<<<17, 256, 0, stream>>>(mp, mp2, tup2, rk2, tup3, rk3, tup4, rk4);
    pinet_fold<<<NO, 1024, 0, stream>>>(w0, w1, w2, w3, w4,
                                        tup2, rk2, tup3, rk3, tup4, rk4, Wh);
    pinet_gemm<<<(NB / 64) * 2, 512, 0, stream>>>(x, Wh, mp, mp2, out);
}